// Round 1
// baseline (8102.712 us; speedup 1.0000x reference)
//
#include <hip/hip_runtime.h>
#include <math.h>

// Problem constants
#define Vv 32000
#define Ee 512
#define Hh 1024
#define H3 3072
#define Ss 64
#define Tt 64
#define Bb 32
#define DEC_T 63     // T-1 teacher-forced steps
#define KS 16        // k-slices for recurrent GEMV partials
#define KSL 64       // slice length (KS*KSL = 1024)
#define PAD_TOK 1
#define NEGV -100000.0f

__device__ __forceinline__ float sigmoidf_(float x) {
  return 1.0f / (1.0f + __expf(-x));
}

// ---------------- transpose: src[R][C] -> dst[C][R] ----------------
__global__ __launch_bounds__(256) void transpose_k(const float* __restrict__ src,
                                                   float* __restrict__ dst,
                                                   int R, int C) {
  __shared__ float tile[32][33];
  int r0 = blockIdx.y * 32, c0 = blockIdx.x * 32;
  int tx = threadIdx.x & 31, ty = threadIdx.x >> 5;
  for (int i = ty; i < 32; i += 8)
    tile[i][tx] = src[(long)(r0 + i) * C + c0 + tx];
  __syncthreads();
  for (int i = ty; i < 32; i += 8)
    dst[(long)(c0 + i) * R + r0 + tx] = tile[tx][i];
}

// ---------------- generic fp32 GEMM: C[m][n] = sum_k A[m][k]*W[n][k] + bias[n]
// A rows optionally gathered via idx (embedding lookup). N must be mult of 128.
template <int ACT>
__global__ __launch_bounds__(256) void gemm_nt(
    const float* __restrict__ A, const int* __restrict__ idx, int lda,
    const float* __restrict__ W, int ldw,
    const float* __restrict__ bias,
    float* __restrict__ C, long ldc,
    int M, int N, int K) {
  __shared__ float As[8][132];
  __shared__ float Ws[8][132];
  int tid = threadIdx.x;
  int n0 = blockIdx.x * 128;
  int m0 = blockIdx.y * 128;
  int sr = tid >> 1;          // 0..127 staged row
  int sk = (tid & 1) * 4;     // 0 or 4
  int am = m0 + sr;
  bool aval = am < M;
  int amc = aval ? am : (M - 1);
  const float* arow = A + (idx ? (long)idx[amc] * lda : (long)amc * lda);
  const float* wrow = W + (long)(n0 + sr) * ldw;
  int tx = tid & 15, ty = tid >> 4;
  float acc[8][8];
#pragma unroll
  for (int i = 0; i < 8; i++)
#pragma unroll
    for (int j = 0; j < 8; j++) acc[i][j] = 0.f;

  for (int k0 = 0; k0 < K; k0 += 8) {
    float4 av = aval ? *(const float4*)(arow + k0 + sk) : make_float4(0.f, 0.f, 0.f, 0.f);
    float4 wv = *(const float4*)(wrow + k0 + sk);
    __syncthreads();
    As[sk + 0][sr] = av.x; As[sk + 1][sr] = av.y; As[sk + 2][sr] = av.z; As[sk + 3][sr] = av.w;
    Ws[sk + 0][sr] = wv.x; Ws[sk + 1][sr] = wv.y; Ws[sk + 2][sr] = wv.z; Ws[sk + 3][sr] = wv.w;
    __syncthreads();
#pragma unroll
    for (int k = 0; k < 8; k++) {
      float a[8], w[8];
      *(float4*)(a) = *(const float4*)&As[k][ty * 8];
      *(float4*)(a + 4) = *(const float4*)&As[k][ty * 8 + 4];
      *(float4*)(w) = *(const float4*)&Ws[k][tx * 8];
      *(float4*)(w + 4) = *(const float4*)&Ws[k][tx * 8 + 4];
#pragma unroll
      for (int i = 0; i < 8; i++)
#pragma unroll
        for (int j = 0; j < 8; j++) acc[i][j] = fmaf(a[i], w[j], acc[i][j]);
    }
  }
#pragma unroll
  for (int i = 0; i < 8; i++) {
    int m = m0 + ty * 8 + i;
    if (m < M) {
      float* crow = C + (long)m * ldc + n0 + tx * 8;
#pragma unroll
      for (int j = 0; j < 8; j++) {
        float v = acc[i][j] + bias[n0 + tx * 8 + j];
        if (ACT == 1) v = tanhf(v);
        crow[j] = v;
      }
    }
  }
}

// ---------------- recurrent partial GEMV:
// part[ks][b][j] = sum_{k in slice ks} x[b][k] * Wt[k][j]
// Wt is pre-transposed [1024][3072] so W loads are coalesced float4.
// grid: (12 j-tiles of 256, KS slices, z selects one of two problems)
__global__ __launch_bounds__(256) void rec_gemv(
    const float* __restrict__ x0, const float* __restrict__ Wt0, float* __restrict__ p0,
    const float* __restrict__ x1, const float* __restrict__ Wt1, float* __restrict__ p1) {
  const float* x = (blockIdx.z == 0) ? x0 : x1;
  const float* Wt = (blockIdx.z == 0) ? Wt0 : Wt1;
  float* part = (blockIdx.z == 0) ? p0 : p1;
  int ks = blockIdx.y;
  int j0 = blockIdx.x * 256;
  int tid = threadIdx.x;
  int txj = tid & 63;   // j group -> all lanes of a wave share bg => x broadcast
  int bg = tid >> 6;    // 0..3  -> 8 batches each
  int j = j0 + txj * 4;
  __shared__ float xs[32][68];
  {
    int r = tid >> 3;
    int c = (tid & 7) * 8;
    const float* xp = x + r * Hh + ks * KSL + c;
    float4 v0 = *(const float4*)(xp);
    float4 v1 = *(const float4*)(xp + 4);
    *(float4*)&xs[r][c] = v0;
    *(float4*)&xs[r][c + 4] = v1;
  }
  __syncthreads();
  float acc[8][4];
#pragma unroll
  for (int bb = 0; bb < 8; bb++)
#pragma unroll
    for (int q = 0; q < 4; q++) acc[bb][q] = 0.f;
  const float* wp = Wt + (long)(ks * KSL) * H3 + j;
#pragma unroll 4
  for (int k = 0; k < KSL; k++) {
    float4 w = *(const float4*)(wp);
    wp += H3;
#pragma unroll
    for (int bb = 0; bb < 8; bb++) {
      float xv = xs[bg * 8 + bb][k];
      acc[bb][0] = fmaf(xv, w.x, acc[bb][0]);
      acc[bb][1] = fmaf(xv, w.y, acc[bb][1]);
      acc[bb][2] = fmaf(xv, w.z, acc[bb][2]);
      acc[bb][3] = fmaf(xv, w.w, acc[bb][3]);
    }
  }
#pragma unroll
  for (int bb = 0; bb < 8; bb++) {
    int b = bg * 8 + bb;
    float4 v;
    v.x = acc[bb][0]; v.y = acc[bb][1]; v.z = acc[bb][2]; v.w = acc[bb][3];
    *(float4*)&part[((long)ks * Bb + b) * H3 + j] = v;
  }
}

// ---------------- GRU layer0 update: gx precomputed, gh from partials. in-place h.
__global__ __launch_bounds__(256) void gru_update0(
    const float* __restrict__ gx, const float* __restrict__ part,
    const float* __restrict__ bhh, float* __restrict__ h) {
  int t = blockIdx.x * 256 + threadIdx.x;
  int b = t >> 10, i = t & 1023;
  float hr = bhh[i], hz = bhh[Hh + i], hn = bhh[2 * Hh + i];
#pragma unroll 4
  for (int ks = 0; ks < KS; ks++) {
    const float* p = part + ((long)ks * Bb + b) * H3 + i;
    hr += p[0]; hz += p[Hh]; hn += p[2 * Hh];
  }
  const float* g = gx + (long)b * H3 + i;
  float r = sigmoidf_(g[0] + hr);
  float z = sigmoidf_(g[Hh] + hz);
  float n = tanhf(g[2 * Hh] + r * hn);
  h[t] = (1.f - z) * n + z * h[t];
}

// ---------------- GRU layer1 update: both gx and gh from partials. in-place h,
// plus secondary store (enc_out row or h1cat first half).
__global__ __launch_bounds__(256) void gru_update1(
    const float* __restrict__ pgx, const float* __restrict__ pgh,
    const float* __restrict__ bih, const float* __restrict__ bhh,
    float* __restrict__ h, float* __restrict__ out2, long os) {
  int t = blockIdx.x * 256 + threadIdx.x;
  int b = t >> 10, i = t & 1023;
  float xr = bih[i], xz = bih[Hh + i], xn = bih[2 * Hh + i];
  float hr = bhh[i], hz = bhh[Hh + i], hn = bhh[2 * Hh + i];
#pragma unroll 4
  for (int ks = 0; ks < KS; ks++) {
    const float* px = pgx + ((long)ks * Bb + b) * H3 + i;
    const float* ph = pgh + ((long)ks * Bb + b) * H3 + i;
    xr += px[0]; xz += px[Hh]; xn += px[2 * Hh];
    hr += ph[0]; hz += ph[Hh]; hn += ph[2 * Hh];
  }
  float r = sigmoidf_(xr + hr);
  float z = sigmoidf_(xz + hz);
  float n = tanhf(xn + r * hn);
  float hv = (1.f - z) * n + z * h[t];
  h[t] = hv;
  out2[(long)b * os + i] = hv;
}

// ---------------- batched attention scores + masked softmax. one block per (t,b).
__global__ __launch_bounds__(256) void attn_kernel(
    const float* __restrict__ h1cat,   // [2016][2048], first half = h1
    const float* __restrict__ enc_out, // [64][32][1024]
    const int* __restrict__ src_tok,   // [64][32]
    float* __restrict__ attn) {        // [2016][64]
  int tb = blockIdx.x;
  int b = tb & 31;
  __shared__ float hs[1024];
  __shared__ float sc[64][4];
  __shared__ float red[64];
  int tid = threadIdx.x;
  const float* h1 = h1cat + (long)tb * 2048;
  for (int i = tid; i < 1024; i += 256) hs[i] = h1[i];
  __syncthreads();
  int s = tid >> 2, q = tid & 3;
  const float* eo = enc_out + ((long)s * Bb + b) * Hh + q * 256;
  float p = 0.f;
  for (int k = 0; k < 256; k += 4) {
    float4 e = *(const float4*)(eo + k);
    const float* hq = hs + q * 256 + k;
    p += e.x * hq[0] + e.y * hq[1] + e.z * hq[2] + e.w * hq[3];
  }
  sc[s][q] = p;
  __syncthreads();
  if (tid < 64) {
    float v = sc[tid][0] + sc[tid][1] + sc[tid][2] + sc[tid][3];
    bool m = (src_tok[tid * Bb + b] != PAD_TOK);
    red[tid] = m ? v : NEGV;
  }
  __syncthreads();
  if (tid < 64) {
    float v = red[tid];
    float mx = v;
    for (int o = 32; o; o >>= 1) mx = fmaxf(mx, __shfl_xor(mx, o));
    float e = __expf(v - mx);
    float sum = e;
    for (int o = 32; o; o >>= 1) sum += __shfl_xor(sum, o);
    attn[(long)tb * 64 + tid] = e / sum;
  }
}

// ---------------- context: ctx[tb][k] = sum_s attn[tb][s]*enc_out[s][b][k]
// writes into second half of h1cat row.
__global__ __launch_bounds__(256) void ctx_kernel(
    const float* __restrict__ attn, const float* __restrict__ enc_out,
    float* __restrict__ h1cat) {
  int tb = blockIdx.x;
  int b = tb & 31;
  __shared__ float as[64];
  int tid = threadIdx.x;
  if (tid < 64) as[tid] = attn[(long)tb * 64 + tid];
  __syncthreads();
  float4 acc = make_float4(0.f, 0.f, 0.f, 0.f);
  const float* eo = enc_out + (long)b * Hh + tid * 4;
  for (int s = 0; s < 64; s++) {
    float a = as[s];
    float4 e = *(const float4*)(eo + (long)s * Bb * Hh);
    acc.x += a * e.x; acc.y += a * e.y; acc.z += a * e.z; acc.w += a * e.w;
  }
  *(float4*)(h1cat + (long)tb * 2048 + 1024 + tid * 4) = acc;
}

extern "C" void kernel_launch(void* const* d_in, const int* in_sizes, int n_in,
                              void* d_out, int out_size, void* d_ws, size_t ws_size,
                              hipStream_t stream) {
  const int* src_tok = (const int*)d_in[0];
  const int* tgt_tok = (const int*)d_in[1];
  const float* enc_emb = (const float*)d_in[2];
  const float* eWih0 = (const float*)d_in[3];
  const float* eWhh0 = (const float*)d_in[4];
  const float* ebih0 = (const float*)d_in[5];
  const float* ebhh0 = (const float*)d_in[6];
  const float* eWih1 = (const float*)d_in[7];
  const float* eWhh1 = (const float*)d_in[8];
  const float* ebih1 = (const float*)d_in[9];
  const float* ebhh1 = (const float*)d_in[10];
  const float* dec_emb = (const float*)d_in[11];
  const float* dWih0 = (const float*)d_in[12];
  const float* dWhh0 = (const float*)d_in[13];
  const float* dbih0 = (const float*)d_in[14];
  const float* dbhh0 = (const float*)d_in[15];
  const float* dWih1 = (const float*)d_in[16];
  const float* dWhh1 = (const float*)d_in[17];
  const float* dbih1 = (const float*)d_in[18];
  const float* dbhh1 = (const float*)d_in[19];
  const float* Wc = (const float*)d_in[20];
  const float* bc = (const float*)d_in[21];
  const float* Wo = (const float*)d_in[22];
  const float* bo = (const float*)d_in[23];
  float* out = (float*)d_out;

  // workspace layout (floats); total ~38.4M floats (~154 MB)
  float* w = (float*)d_ws;
  size_t o = 0;
  const size_t WT = (size_t)Hh * H3;  // 3,145,728
  float* eWhh0t = w + o; o += WT;
  float* eWih1t = w + o; o += WT;
  float* eWhh1t = w + o; o += WT;
  float* dWhh0t = w + o; o += WT;
  float* dWih1t = w + o; o += WT;
  float* dWhh1t = w + o; o += WT;
  float* gx0 = w + o;    o += (size_t)Ss * Bb * H3;       // reused enc then dec
  float* enc_out = w + o; o += (size_t)Ss * Bb * Hh;
  float* h1cat = w + o;  o += (size_t)DEC_T * Bb * 2 * Hh;
  float* h0buf = w + o;  o += (size_t)Bb * Hh;
  float* h1buf = w + o;  o += (size_t)Bb * Hh;            // adjacent to h0buf
  float* pgh0 = w + o;   o += (size_t)KS * Bb * H3;
  float* pgx1 = w + o;   o += (size_t)KS * Bb * H3;
  float* pgh1 = w + o;   o += (size_t)KS * Bb * H3;
  float* attnb = w + o;  o += (size_t)DEC_T * Bb * Ss;
  float* ccb = w + o;    o += (size_t)DEC_T * Bb * Hh;

  // zero first output timestep and initial hidden state (ws/out are poisoned)
  hipMemsetAsync(out, 0, (size_t)Bb * Vv * sizeof(float), stream);
  hipMemsetAsync(h0buf, 0, (size_t)2 * Bb * Hh * sizeof(float), stream);

  // one-time weight transposes [3072][1024] -> [1024][3072]
  dim3 tg(Hh / 32, H3 / 32);
  transpose_k<<<tg, 256, 0, stream>>>(eWhh0, eWhh0t, H3, Hh);
  transpose_k<<<tg, 256, 0, stream>>>(eWih1, eWih1t, H3, Hh);
  transpose_k<<<tg, 256, 0, stream>>>(eWhh1, eWhh1t, H3, Hh);
  transpose_k<<<tg, 256, 0, stream>>>(dWhh0, dWhh0t, H3, Hh);
  transpose_k<<<tg, 256, 0, stream>>>(dWih1, dWih1t, H3, Hh);
  transpose_k<<<tg, 256, 0, stream>>>(dWhh1, dWhh1t, H3, Hh);

  // encoder input gates for all timesteps: gx0 = emb[src] @ Wih0^T + bih0
  gemm_nt<0><<<dim3(H3 / 128, 16), 256, 0, stream>>>(
      enc_emb, src_tok, Ee, eWih0, Ee, ebih0, gx0, (long)H3, Ss * Bb, H3, Ee);

  // ---- encoder recurrence ----
  for (int s = 0; s < Ss; s++) {
    rec_gemv<<<dim3(12, KS, 1), 256, 0, stream>>>(h0buf, eWhh0t, pgh0,
                                                  h0buf, eWhh0t, pgh0);
    gru_update0<<<128, 256, 0, stream>>>(gx0 + (size_t)s * Bb * H3, pgh0, ebhh0, h0buf);
    rec_gemv<<<dim3(12, KS, 2), 256, 0, stream>>>(h0buf, eWih1t, pgx1,
                                                  h1buf, eWhh1t, pgh1);
    gru_update1<<<128, 256, 0, stream>>>(pgx1, pgh1, ebih1, ebhh1, h1buf,
                                         enc_out + (size_t)s * Bb * Hh, (long)Hh);
  }

  // decoder input gates for all 63 steps (reuses gx0 buffer; stream-ordered)
  gemm_nt<0><<<dim3(H3 / 128, 16), 256, 0, stream>>>(
      dec_emb, tgt_tok, Ee, dWih0, Ee, dbih0, gx0, (long)H3, DEC_T * Bb, H3, Ee);

  // ---- decoder recurrence (hidden carries over from encoder) ----
  for (int t = 0; t < DEC_T; t++) {
    rec_gemv<<<dim3(12, KS, 1), 256, 0, stream>>>(h0buf, dWhh0t, pgh0,
                                                  h0buf, dWhh0t, pgh0);
    gru_update0<<<128, 256, 0, stream>>>(gx0 + (size_t)t * Bb * H3, pgh0, dbhh0, h0buf);
    rec_gemv<<<dim3(12, KS, 2), 256, 0, stream>>>(h0buf, dWih1t, pgx1,
                                                  h1buf, dWhh1t, pgh1);
    gru_update1<<<128, 256, 0, stream>>>(pgx1, pgh1, dbih1, dbhh1, h1buf,
                                         h1cat + (size_t)t * Bb * 2 * Hh, (long)(2 * Hh));
  }

  // ---- batched attention + context (deferred: doesn't feed the recurrence) ----
  attn_kernel<<<DEC_T * Bb, 256, 0, stream>>>(h1cat, enc_out, src_tok, attnb);
  ctx_kernel<<<DEC_T * Bb, 256, 0, stream>>>(attnb, enc_out, h1cat);

  // cc = tanh([h1, ctx] @ Wc^T + bc)
  gemm_nt<1><<<dim3(Hh / 128, 16), 256, 0, stream>>>(
      h1cat, nullptr, 2 * Hh, Wc, 2 * Hh, bc, ccb, (long)Hh, DEC_T * Bb, Hh, 2 * Hh);

  // logits = cc @ Wo^T + bo  -> rows [1..63] of output
  gemm_nt<0><<<dim3(Vv / 128, 16), 256, 0, stream>>>(
      ccb, nullptr, Hh, Wo, Hh, bo, out + (size_t)Bb * Vv, (long)Vv, DEC_T * Bb, Vv, Hh);
}